// Round 14
// baseline (192.288 us; speedup 1.0000x reference)
//
#include <hip/hip_runtime.h>

typedef __bf16 bf16;
typedef __attribute__((ext_vector_type(8))) __bf16 bf16x8;
typedef __attribute__((ext_vector_type(8))) ushort ushort8v;
typedef __attribute__((ext_vector_type(4))) ushort ushort4v;
typedef __attribute__((ext_vector_type(2))) uint uint2v;
typedef __attribute__((ext_vector_type(4))) float f32x4;

constexpr int S_LEN = 2048;
constexpr int DH    = 64;
constexpr int KVBLK = 64;
constexpr int NT    = S_LEN / KVBLK;             // 32 kv tiles
constexpr int QW    = 32;                        // q-rows per wave (2 frags)
constexpr float QSCALE = 0.125f * 1.44269504088896f;  // 1/sqrt(64) * log2(e)
constexpr float NEG    = -1.44269504e9f;         // -1e9 in log2 domain
constexpr float THR    = 8.0f;                   // defer-max threshold (T13)
constexpr size_t TILE_BYTES = (size_t)KVBLK * DH * 2;       // 8 KiB
constexpr size_t KV_BYTES   = (size_t)64 * NT * TILE_BYTES; // 16 MiB per tensor

__device__ __forceinline__ ushort bfb(float f) {
  bf16 b = (bf16)f;
  return __builtin_bit_cast(ushort, b);
}
__device__ __forceinline__ int SWZ(int row) {
  return ((row & 7) ^ ((row >> 3) & 7)) << 4;
}
__device__ __forceinline__ uint cvtpk(float lo, float hi) {
  uint r;
  asm("v_cvt_pk_bf16_f32 %0, %1, %2" : "=v"(r) : "v"(lo), "v"(hi));
  return r;
}

// ---- prepass: parallel all-ones tile flags, atomicOr into per-qt bitmask ----
__global__ __launch_bounds__(256)
void mask_flags(const int* __restrict__ M, uint* __restrict__ F) {
  const int qt  = blockIdx.x;
  const int kt0 = blockIdx.y * 4;
  const int tid = threadIdx.x;
  const int r  = tid >> 2;
  const int c0 = (tid & 3) * 16;
  __shared__ int s[4];
  uint bits = 0;
  for (int i = 0; i < 4; ++i) {
    const int kt = kt0 + i;
    const int* row = M + (size_t)(qt * 64 + r) * S_LEN + kt * 64 + c0;
    int ok = 1;
#pragma unroll
    for (int j = 0; j < 4; ++j) {
      int4 v = *(const int4*)(row + j * 4);
      ok &= (v.x != 0) & (v.y != 0) & (v.z != 0) & (v.w != 0);
    }
    ok = __all(ok) ? 1 : 0;
    if ((tid & 63) == 0) s[tid >> 6] = ok;
    __syncthreads();
    if (s[0] & s[1] & s[2] & s[3]) bits |= 1u << kt;
    __syncthreads();
  }
  if (tid == 0) atomicOr(&F[qt], bits);
}

// ---- prepass: K -> bf16 swizzled tile blobs; V -> V^T bf16 swizzled blobs ----
__global__ __launch_bounds__(256)
void cvt_kv(const float* __restrict__ K, const float* __restrict__ V,
            char* __restrict__ kws, char* __restrict__ vws) {
  const int t = blockIdx.x, bh = blockIdx.y, tid = threadIdx.x;
  const float* Kb = K + ((size_t)bh * S_LEN + t * KVBLK) * DH;
  const float* Vb = V + ((size_t)bh * S_LEN + t * KVBLK) * DH;
  char* kd = kws + ((size_t)bh * NT + t) * TILE_BYTES;
  char* vd = vws + ((size_t)bh * NT + t) * TILE_BYTES;

  const int kr0 = tid >> 3, kc8 = tid & 7;
#pragma unroll
  for (int h = 0; h < 2; ++h) {
    const int row = kr0 + 32 * h;
    const float* kp = Kb + (size_t)row * DH + kc8 * 8;
    float4 a = *(const float4*)kp;
    float4 b = *(const float4*)(kp + 4);
    ushort8v pk;
    pk[0]=bfb(a.x); pk[1]=bfb(a.y); pk[2]=bfb(a.z); pk[3]=bfb(a.w);
    pk[4]=bfb(b.x); pk[5]=bfb(b.y); pk[6]=bfb(b.z); pk[7]=bfb(b.w);
    *(ushort8v*)(kd + row * 128 + ((kc8 * 16) ^ SWZ(row))) = pk;
  }
  const int vr = (tid >> 4) * 4, vc = (tid & 15) * 4;
  float rr[4][4];
#pragma unroll
  for (int i = 0; i < 4; ++i)
    *(float4*)rr[i] = *(const float4*)(Vb + (size_t)(vr + i) * DH + vc);
#pragma unroll
  for (int c = 0; c < 4; ++c) {
    const int d = vc + c;
    ushort4v p4;
    p4[0]=bfb(rr[0][c]); p4[1]=bfb(rr[1][c]);
    p4[2]=bfb(rr[2][c]); p4[3]=bfb(rr[3][c]);
    *(ushort4v*)(vd + d * 128 + ((vr * 2) ^ SWZ(d))) = p4;
  }
}

// ---- main: barrier-free, 1 wave/wg, 32 q-rows/wave, K/V direct from L2 ----
// NOTE: launch_bounds min-waves MUST stay 1 — higher values cap VGPRs and
// spill (R9: (128,4)->64cap; R12: (64,2)->128cap). R13: VGPR>200 halves
// residency. Target: ~140-170 VGPR, 3 waves/SIMD.
__global__ __launch_bounds__(64, 1)
void attn_fwd_direct(const float* __restrict__ Q, const int* __restrict__ M,
                     const uint* __restrict__ F, const char* __restrict__ kws,
                     const char* __restrict__ vws, float* __restrict__ O)
{
  __shared__ __align__(16) uint pbw[QW * 32];   // 4 KB, this wave's P^T

  const int lane = threadIdx.x & 63;
  const int qr   = lane & 15;
  const int kg   = lane >> 4;

  // XCD-aware bijective swizzle (4096 % 8 == 0)
  const int bid = blockIdx.x;
  const int nid = (bid & 7) * 512 + (bid >> 3);
  const int q0  = (nid & 63) * QW;
  const int bh  = nid >> 6;

  const float* Qb = Q + (size_t)bh * S_LEN * DH;
  const uint fmask = F[q0 >> 6];

  const char* kbase = kws + (size_t)bh * NT * TILE_BYTES;
  const char* vbase = vws + (size_t)bh * NT * TILE_BYTES;

  // ---- Q fragments: rows q0 + f*16 + qr ----
  bf16x8 qf[2][2];
#pragma unroll
  for (int f = 0; f < 2; ++f) {
    const float* qp = Qb + (size_t)(q0 + f * 16 + qr) * DH + kg * 8;
#pragma unroll
    for (int ks = 0; ks < 2; ++ks) {
      float4 a = *(const float4*)(qp + ks * 32);
      float4 b = *(const float4*)(qp + ks * 32 + 4);
      bf16x8 t2;
      t2[0]=(bf16)(a.x*QSCALE); t2[1]=(bf16)(a.y*QSCALE);
      t2[2]=(bf16)(a.z*QSCALE); t2[3]=(bf16)(a.w*QSCALE);
      t2[4]=(bf16)(b.x*QSCALE); t2[5]=(bf16)(b.y*QSCALE);
      t2[6]=(bf16)(b.z*QSCALE); t2[7]=(bf16)(b.w*QSCALE);
      qf[f][ks] = t2;
    }
  }

  f32x4 acc[2][4];
#pragma unroll
  for (int f = 0; f < 2; ++f)
#pragma unroll
    for (int nt = 0; nt < 4; ++nt) { f32x4 z = {0.f,0.f,0.f,0.f}; acc[f][nt] = z; }
  float mrow[2] = {-1e30f, -1e30f};
  float rsum[2] = {0.f, 0.f};

  // fragment byte offsets within a tile blob (loop-invariant)
  int lofs[4][2];
#pragma unroll
  for (int x = 0; x < 4; ++x) {
    const int row = 16 * x + qr;
    const int sw  = SWZ(row);
#pragma unroll
    for (int ks = 0; ks < 2; ++ks)
      lofs[x][ks] = row * 128 + ((kg * 16 + 64 * ks) ^ sw);
  }
  const int psw = (qr & 7) << 4;

  for (int t = 0; t < NT; ++t) {
    const char* kt = kbase + (size_t)t * TILE_BYTES;
    const char* vt = vbase + (size_t)t * TILE_BYTES;

    // ---- S^T = K Q^T : each kf fragment feeds 2 MFMAs ----
    f32x4 sc[2][4];
#pragma unroll
    for (int f = 0; f < 2; ++f)
#pragma unroll
      for (int ct = 0; ct < 4; ++ct) { f32x4 z = {0.f,0.f,0.f,0.f}; sc[f][ct] = z; }

    __builtin_amdgcn_s_setprio(1);
#pragma unroll
    for (int ct = 0; ct < 4; ++ct)
#pragma unroll
      for (int ks = 0; ks < 2; ++ks) {
        bf16x8 kf = *(const bf16x8*)(kt + lofs[ct][ks]);
        sc[0][ct] = __builtin_amdgcn_mfma_f32_16x16x32_bf16(kf, qf[0][ks], sc[0][ct], 0,0,0);
        sc[1][ct] = __builtin_amdgcn_mfma_f32_16x16x32_bf16(kf, qf[1][ks], sc[1][ct], 0,0,0);
      }
    __builtin_amdgcn_s_setprio(0);

    // ---- issue V fragment loads now; latency hides under softmax ----
    bf16x8 vfr[4][2];
#pragma unroll
    for (int nt = 0; nt < 4; ++nt)
#pragma unroll
      for (int ks = 0; ks < 2; ++ks)
        vfr[nt][ks] = *(const bf16x8*)(vt + lofs[nt][ks]);

    const bool allset = ((fmask >> t) & 1u) != 0u;

    // ---- per-frag in-register online softmax + P pack to LDS ----
#pragma unroll
    for (int f = 0; f < 2; ++f) {
      if (!allset) {
        const size_t mo = (size_t)(q0 + f * 16 + qr) * S_LEN + t * KVBLK + 4 * kg;
#pragma unroll
        for (int ct = 0; ct < 4; ++ct)
#pragma unroll
          for (int r = 0; r < 4; ++r)
            if (M[mo + 16 * ct + r] == 0) sc[f][ct][r] = NEG;
      }

      float a0 = fmaxf(fmaxf(sc[f][0][0], sc[f][0][1]), sc[f][0][2]);
      float a1 = fmaxf(fmaxf(sc[f][0][3], sc[f][1][0]), sc[f][1][1]);
      float a2 = fmaxf(fmaxf(sc[f][1][2], sc[f][1][3]), sc[f][2][0]);
      float a3 = fmaxf(fmaxf(sc[f][2][1], sc[f][2][2]), sc[f][2][3]);
      float a4 = fmaxf(fmaxf(sc[f][3][0], sc[f][3][1]), sc[f][3][2]);
      float lm = fmaxf(fmaxf(a0, a1), a2);
      lm = fmaxf(fmaxf(lm, a3), a4);
      lm = fmaxf(lm, sc[f][3][3]);
      lm = fmaxf(lm, __shfl_xor(lm, 16));
      lm = fmaxf(lm, __shfl_xor(lm, 32));

      if (!__all(lm - mrow[f] <= THR)) {   // defer-max (T13)
        const float mnew = fmaxf(mrow[f], lm);
        const float corr = __builtin_amdgcn_exp2f(mrow[f] - mnew);
        rsum[f] *= corr;
#pragma unroll
        for (int nt = 0; nt < 4; ++nt) acc[f][nt] *= corr;
        mrow[f] = mnew;
      }

      float p[4][4];
      float ps = 0.f;
#pragma unroll
      for (int ct = 0; ct < 4; ++ct)
#pragma unroll
        for (int r = 0; r < 4; ++r) {
          p[ct][r] = __builtin_amdgcn_exp2f(sc[f][ct][r] - mrow[f]);
          ps += p[ct][r];
        }
      rsum[f] += ps;

      char* pb = (char*)pbw + (f * 16 + qr) * 128;
#pragma unroll
      for (int ct = 0; ct < 4; ++ct) {
        uint2v d2;
        d2[0] = cvtpk(p[ct][0], p[ct][1]);
        d2[1] = cvtpk(p[ct][2], p[ct][3]);
        *(uint2v*)(pb + ((32 * ct + 8 * kg) ^ psw)) = d2;
      }
    }

    // ---- O^T += V^T P^T : each vf fragment feeds 2 MFMAs ----
    __builtin_amdgcn_s_setprio(1);
#pragma unroll
    for (int ks = 0; ks < 2; ++ks) {
      bf16x8 pf0 = *(const bf16x8*)((char*)pbw + (0 * 16 + qr) * 128 + ((kg * 16 + 64 * ks) ^ psw));
      bf16x8 pf1 = *(const bf16x8*)((char*)pbw + (1 * 16 + qr) * 128 + ((kg * 16 + 64 * ks) ^ psw));
#pragma unroll
      for (int nt = 0; nt < 4; ++nt) {
        bf16x8 vf = vfr[nt][ks];
        acc[0][nt] = __builtin_amdgcn_mfma_f32_16x16x32_bf16(vf, pf0, acc[0][nt], 0,0,0);
        acc[1][nt] = __builtin_amdgcn_mfma_f32_16x16x32_bf16(vf, pf1, acc[1][nt], 0,0,0);
      }
    }
    __builtin_amdgcn_s_setprio(0);
  }

  // ---- epilogue ----
#pragma unroll
  for (int f = 0; f < 2; ++f) {
    float rs = rsum[f];
    rs += __shfl_xor(rs, 16);
    rs += __shfl_xor(rs, 32);
    const float inv = 1.0f / rs;
    float* Ob = O + ((size_t)bh * S_LEN + q0 + f * 16 + qr) * DH;
#pragma unroll
    for (int nt = 0; nt < 4; ++nt) {
      float4 o = { acc[f][nt][0] * inv, acc[f][nt][1] * inv,
                   acc[f][nt][2] * inv, acc[f][nt][3] * inv };
      *(float4*)(Ob + 16 * nt + 4 * kg) = o;
    }
  }
}

// ---- fallback (no workspace): single-buffer kernel, fp32-direct staging ----
__global__ __launch_bounds__(256, 4)
void attn_fwd_fb(const float* __restrict__ Q, const float* __restrict__ K,
                 const float* __restrict__ V, const int* __restrict__ M,
                 float* __restrict__ O)
{
  __shared__ __align__(16) ushort kb[KVBLK * DH];
  __shared__ __align__(16) ushort vb[DH * KVBLK];
  __shared__ __align__(16) uint   pbw[4 * 32 * 32];

  const int tid  = threadIdx.x;
  const int lane = tid & 63;
  const int w    = tid >> 6;
  const int qr   = lane & 15;
  const int kg   = lane >> 4;

  const int flat = blockIdx.y * gridDim.x + blockIdx.x;
  const int nid  = (flat & 7) * 128 + (flat >> 3);
  const int q0   = (nid & 15) * 128;
  const int bh   = nid >> 4;

  const float* Qb = Q + ((size_t)bh * S_LEN) * DH;
  const float* Kb = K + ((size_t)bh * S_LEN) * DH;
  const float* Vb = V + ((size_t)bh * S_LEN) * DH;

  bf16x8 qf[2][2];
#pragma unroll
  for (int f = 0; f < 2; ++f) {
    const float* qp = Qb + (size_t)(q0 + w * 32 + f * 16 + qr) * DH + kg * 8;
#pragma unroll
    for (int ks = 0; ks < 2; ++ks) {
      float4 a = *(const float4*)(qp + ks * 32);
      float4 b = *(const float4*)(qp + ks * 32 + 4);
      bf16x8 t2;
      t2[0]=(bf16)(a.x*QSCALE); t2[1]=(bf16)(a.y*QSCALE);
      t2[2]=(bf16)(a.z*QSCALE); t2[3]=(bf16)(a.w*QSCALE);
      t2[4]=(bf16)(b.x*QSCALE); t2[5]=(bf16)(b.y*QSCALE);
      t2[6]=(bf16)(b.z*QSCALE); t2[7]=(bf16)(b.w*QSCALE);
      qf[f][ks] = t2;
    }
  }

  f32x4 acc[2][4];
#pragma unroll
  for (int f = 0; f < 2; ++f)
#pragma unroll
    for (int nt = 0; nt < 4; ++nt) { f32x4 z = {0.f,0.f,0.f,0.f}; acc[f][nt] = z; }
  float mrow[2] = {-1e30f, -1e30f};
  float rsum[2] = {0.f, 0.f};

  int lofs[4][2];
#pragma unroll
  for (int x = 0; x < 4; ++x) {
    const int row = 16 * x + qr;
    const int sw  = SWZ(row);
#pragma unroll
    for (int ks = 0; ks < 2; ++ks)
      lofs[x][ks] = row * 128 + ((kg * 16 + 64 * ks) ^ sw);
  }
  char* pb0 = (char*)pbw + (w * 32 + qr) * 128;
  char* pb1 = pb0 + 16 * 128;
  const int psw = (qr & 7) << 4;

  const int kr0 = tid >> 3, kc8 = tid & 7;
  const int vr = (tid >> 4) * 4, vc = (tid & 15) * 4;

  for (int t = 0; t < NT; ++t) {
    const int kv0 = t * KVBLK;
#pragma unroll
    for (int h = 0; h < 2; ++h) {
      const int row = kr0 + 32 * h;
      const float* kp = Kb + (size_t)(kv0 + row) * DH + kc8 * 8;
      float4 a = *(const float4*)kp;
      float4 b = *(const float4*)(kp + 4);
      ushort8v pk;
      pk[0]=bfb(a.x); pk[1]=bfb(a.y); pk[2]=bfb(a.z); pk[3]=bfb(a.w);
      pk[4]=bfb(b.x); pk[5]=bfb(b.y); pk[6]=bfb(b.z); pk[7]=bfb(b.w);
      *(ushort8v*)((char*)kb + row * 128 + ((kc8 * 16) ^ SWZ(row))) = pk;
    }
    float rr[4][4];
#pragma unroll
    for (int i = 0; i < 4; ++i)
      *(float4*)rr[i] = *(const float4*)(Vb + (size_t)(kv0 + vr + i) * DH + vc);
#pragma unroll
    for (int c = 0; c < 4; ++c) {
      const int d = vc + c;
      ushort4v p4;
      p4[0]=bfb(rr[0][c]); p4[1]=bfb(rr[1][c]);
      p4[2]=bfb(rr[2][c]); p4[3]=bfb(rr[3][c]);
      *(ushort4v*)((char*)vb + d * 128 + ((vr * 2) ^ SWZ(d))) = p4;
    }
    __syncthreads();

    f32x4 sc[2][4];
#pragma unroll
    for (int ct = 0; ct < 4; ++ct) {
      f32x4 z = {0.f,0.f,0.f,0.f};
      sc[0][ct] = z; sc[1][ct] = z;
#pragma unroll
      for (int ks = 0; ks < 2; ++ks) {
        bf16x8 kf = *(const bf16x8*)((const char*)kb + lofs[ct][ks]);
        sc[0][ct] = __builtin_amdgcn_mfma_f32_16x16x32_bf16(kf, qf[0][ks], sc[0][ct], 0,0,0);
        sc[1][ct] = __builtin_amdgcn_mfma_f32_16x16x32_bf16(kf, qf[1][ks], sc[1][ct], 0,0,0);
      }
    }

#pragma unroll
    for (int f = 0; f < 2; ++f) {
      const size_t mo = (size_t)(q0 + w * 32 + f * 16 + qr) * S_LEN + t * KVBLK + 4 * kg;
#pragma unroll
      for (int ct = 0; ct < 4; ++ct)
#pragma unroll
        for (int r = 0; r < 4; ++r)
          if (M[mo + 16 * ct + r] == 0) sc[f][ct][r] = NEG;

      float a0 = fmaxf(fmaxf(sc[f][0][0], sc[f][0][1]), sc[f][0][2]);
      float a1 = fmaxf(fmaxf(sc[f][0][3], sc[f][1][0]), sc[f][1][1]);
      float a2 = fmaxf(fmaxf(sc[f][1][2], sc[f][1][3]), sc[f][2][0]);
      float a3 = fmaxf(fmaxf(sc[f][2][1], sc[f][2][2]), sc[f][2][3]);
      float a4 = fmaxf(fmaxf(sc[f][3][0], sc[f][3][1]), sc[f][3][2]);
      float lm = fmaxf(fmaxf(a0, a1), a2);
      lm = fmaxf(fmaxf(lm, a3), a4);
      lm = fmaxf(lm, sc[f][3][3]);
      lm = fmaxf(lm, __shfl_xor(lm, 16));
      lm = fmaxf(lm, __shfl_xor(lm, 32));

      if (!__all(lm - mrow[f] <= THR)) {
        const float mnew = fmaxf(mrow[f], lm);
        const float corr = __builtin_amdgcn_exp2f(mrow[f] - mnew);
        rsum[f] *= corr;
#pragma unroll
        for (int nt = 0; nt < 4; ++nt) acc[f][nt] *= corr;
        mrow[f] = mnew;
      }

      float p[4][4];
      float ps = 0.f;
#pragma unroll
      for (int ct = 0; ct < 4; ++ct)
#pragma unroll
        for (int r = 0; r < 4; ++r) {
          p[ct][r] = __builtin_amdgcn_exp2f(sc[f][ct][r] - mrow[f]);
          ps += p[ct][r];
        }
      rsum[f] += ps;

      char* pb = f ? pb1 : pb0;
#pragma unroll
      for (int ct = 0; ct < 4; ++ct) {
        uint2v d2;
        d2[0] = cvtpk(p[ct][0], p[ct][1]);
        d2[1] = cvtpk(p[ct][2], p[ct][3]);
        *(uint2v*)(pb + ((32 * ct + 8 * kg) ^ psw)) = d2;
      }
    }

#pragma unroll
    for (int ks = 0; ks < 2; ++ks) {
      bf16x8 pf0 = *(const bf16x8*)(pb0 + ((kg * 16 + 64 * ks) ^ psw));
      bf16x8 pf1 = *(const bf16x8*)(pb1 + ((kg * 16 + 64 * ks) ^ psw));
#pragma unroll
      for (int nt = 0; nt < 4; ++nt) {
        bf16x8 vf = *(const bf16x8*)((const char*)vb + lofs[nt][ks]);
        acc[0][nt] = __builtin_amdgcn_mfma_f32_16x16x32_bf16(vf, pf0, acc[0][nt], 0,0,0);
        acc[1][nt] = __builtin_amdgcn_mfma_f32_16x16x32_bf16(vf, pf1, acc[1][nt], 0,0,0);
      }
    }
    __syncthreads();
  }

#pragma unroll
  for (int f = 0; f < 2; ++f) {
    float rs = rsum[f];
    rs += __shfl_xor(rs, 16);
    rs += __shfl_xor(rs, 32);
    const float inv = 1.0f / rs;
    float* Ob = O + ((size_t)bh * S_LEN + q0 + w * 32 + f * 16 + qr) * DH;
#pragma unroll
    for (int nt = 0; nt < 4; ++nt) {
      float4 o = { acc[f][nt][0] * inv, acc[f][nt][1] * inv,
                   acc[f][nt][2] * inv, acc[f][nt][3] * inv };
      *(float4*)(Ob + 16 * nt + 4 * kg) = o;
    }
  }
}

extern "C" void kernel_launch(void* const* d_in, const int* in_sizes, int n_in,
                              void* d_out, int out_size, void* d_ws, size_t ws_size,
                              hipStream_t stream)
{
  const float* Q = (const float*)d_in[0];
  const float* K = (const float*)d_in[1];
  const float* V = (const float*)d_in[2];
  const int*   M = (const int*)d_in[3];
  float* O = (float*)d_out;

  const size_t need = 4096 + 2 * KV_BYTES;
  const bool pre = (d_ws != nullptr) && (ws_size >= need);

  if (pre) {
    uint* F   = (uint*)d_ws;
    char* kws = (char*)d_ws + 4096;
    char* vws = kws + KV_BYTES;
    hipMemsetAsync(F, 0, 32 * sizeof(uint), stream);
    mask_flags<<<dim3(32, 8), 256, 0, stream>>>(M, F);
    cvt_kv<<<dim3(NT, 64), 256, 0, stream>>>(K, V, kws, vws);
    attn_fwd_direct<<<4096, 64, 0, stream>>>(Q, M, F, kws, vws, O);
  } else {
    attn_fwd_fb<<<dim3(16, 64), 256, 0, stream>>>(Q, K, V, M, O);
  }
}

// Round 15
// 126.197 us; speedup vs baseline: 1.5237x; 1.5237x over previous
//
#include <hip/hip_runtime.h>

typedef __bf16 bf16;
typedef __attribute__((ext_vector_type(8))) __bf16 bf16x8;
typedef __attribute__((ext_vector_type(8))) ushort ushort8v;
typedef __attribute__((ext_vector_type(4))) ushort ushort4v;
typedef __attribute__((ext_vector_type(2))) uint uint2v;
typedef __attribute__((ext_vector_type(4))) float f32x4;

constexpr int S_LEN = 2048;
constexpr int DH    = 64;
constexpr int QBLK  = 128;                       // 4 waves x 32 q-rows
constexpr int KVBLK = 64;
constexpr int NWAVE = 4;
constexpr int NT    = S_LEN / KVBLK;             // 32 kv tiles
constexpr float QSCALE = 0.125f * 1.44269504088896f;  // 1/sqrt(64) * log2(e)
constexpr float NEG    = -1.44269504e9f;         // -1e9 in log2 domain
constexpr float THR    = 8.0f;                   // defer-max threshold (T13)
constexpr size_t TILE_BYTES = (size_t)KVBLK * DH * 2;       // 8 KiB
constexpr size_t KV_BYTES   = (size_t)64 * NT * TILE_BYTES; // 16 MiB per tensor

__device__ __forceinline__ ushort bfb(float f) {
  bf16 b = (bf16)f;
  return __builtin_bit_cast(ushort, b);
}
__device__ __forceinline__ int SWZ(int row) {
  return ((row & 7) ^ ((row >> 3) & 7)) << 4;
}
__device__ __forceinline__ uint cvtpk(float lo, float hi) {
  uint r;
  asm("v_cvt_pk_bf16_f32 %0, %1, %2" : "=v"(r) : "v"(lo), "v"(hi));
  return r;
}
__device__ __forceinline__ void gload16(const char* g, void* l) {
  __builtin_amdgcn_global_load_lds(
      (__attribute__((address_space(1))) void*)(g),
      (__attribute__((address_space(3))) void*)(l), 16, 0, 0);
}

// ---- prepass: parallel all-ones tile flags, atomicOr into per-qt bitmask ----
// (R8's version: ~2 us vs the serial R6 one's ~15 us)
__global__ __launch_bounds__(256)
void mask_flags(const int* __restrict__ M, uint* __restrict__ F) {
  const int qt  = blockIdx.x;
  const int kt0 = blockIdx.y * 4;
  const int tid = threadIdx.x;
  const int r  = tid >> 2;
  const int c0 = (tid & 3) * 16;
  __shared__ int s[4];
  uint bits = 0;
  for (int i = 0; i < 4; ++i) {
    const int kt = kt0 + i;
    const int* row = M + (size_t)(qt * 64 + r) * S_LEN + kt * 64 + c0;
    int ok = 1;
#pragma unroll
    for (int j = 0; j < 4; ++j) {
      int4 v = *(const int4*)(row + j * 4);
      ok &= (v.x != 0) & (v.y != 0) & (v.z != 0) & (v.w != 0);
    }
    ok = __all(ok) ? 1 : 0;
    if ((tid & 63) == 0) s[tid >> 6] = ok;
    __syncthreads();
    if (s[0] & s[1] & s[2] & s[3]) bits |= 1u << kt;
    __syncthreads();
  }
  if (tid == 0) atomicOr(&F[qt], bits);
}

// ---- prepass: K -> bf16 swizzled tile blobs; V -> V^T bf16 swizzled blobs ----
__global__ __launch_bounds__(256)
void cvt_kv(const float* __restrict__ K, const float* __restrict__ V,
            char* __restrict__ kws, char* __restrict__ vws) {
  const int t = blockIdx.x, bh = blockIdx.y, tid = threadIdx.x;
  const float* Kb = K + ((size_t)bh * S_LEN + t * KVBLK) * DH;
  const float* Vb = V + ((size_t)bh * S_LEN + t * KVBLK) * DH;
  char* kd = kws + ((size_t)bh * NT + t) * TILE_BYTES;
  char* vd = vws + ((size_t)bh * NT + t) * TILE_BYTES;

  const int kr0 = tid >> 3, kc8 = tid & 7;
#pragma unroll
  for (int h = 0; h < 2; ++h) {
    const int row = kr0 + 32 * h;
    const float* kp = Kb + (size_t)row * DH + kc8 * 8;
    float4 a = *(const float4*)kp;
    float4 b = *(const float4*)(kp + 4);
    ushort8v pk;
    pk[0]=bfb(a.x); pk[1]=bfb(a.y); pk[2]=bfb(a.z); pk[3]=bfb(a.w);
    pk[4]=bfb(b.x); pk[5]=bfb(b.y); pk[6]=bfb(b.z); pk[7]=bfb(b.w);
    *(ushort8v*)(kd + row * 128 + ((kc8 * 16) ^ SWZ(row))) = pk;
  }
  const int vr = (tid >> 4) * 4, vc = (tid & 15) * 4;
  float rr[4][4];
#pragma unroll
  for (int i = 0; i < 4; ++i)
    *(float4*)rr[i] = *(const float4*)(Vb + (size_t)(vr + i) * DH + vc);
#pragma unroll
  for (int c = 0; c < 4; ++c) {
    const int d = vc + c;
    ushort4v p4;
    p4[0]=bfb(rr[0][c]); p4[1]=bfb(rr[1][c]);
    p4[2]=bfb(rr[2][c]); p4[3]=bfb(rr[3][c]);
    *(ushort4v*)(vd + d * 128 + ((vr * 2) ^ SWZ(d))) = p4;
  }
}

// ---- main: R6 kernel VERBATIM (measured 117.7 us, VGPR 60, occ 36%) ----
// LDS staging keeps K/V/P out of registers -> <=64-VGPR bracket -> 16 waves/CU
// ceiling; 4 waves share every staged fragment (each feeds 2 MFMAs).
template<bool PRE>
__global__ __launch_bounds__(256, 4)
void attn_fwd(const float* __restrict__ Q, const float* __restrict__ K,
              const float* __restrict__ V, const int* __restrict__ M,
              const uint* __restrict__ F, const char* __restrict__ kws,
              const char* __restrict__ vws, float* __restrict__ O)
{
  __shared__ __align__(16) ushort kb[KVBLK * DH];        // [kv][d] swizzled
  __shared__ __align__(16) ushort vb[DH * KVBLK];        // [d][kv] swizzled
  __shared__ __align__(16) uint   pbw[NWAVE * 32 * 32];  // 32 q-rows/wave

  const int tid  = threadIdx.x;
  const int lane = tid & 63;
  const int w    = tid >> 6;
  const int qr   = lane & 15;
  const int kg   = lane >> 4;

  // XCD-aware bijective block swizzle (1024 % 8 == 0)
  const int flat = blockIdx.y * gridDim.x + blockIdx.x;
  const int nid  = (flat & 7) * 128 + (flat >> 3);
  const int q0   = (nid & 15) * QBLK;
  const int bh   = nid >> 4;

  const float* Qb = Q + ((size_t)bh * S_LEN) * DH;
  const float* Kb = K + ((size_t)bh * S_LEN) * DH;
  const float* Vb = V + ((size_t)bh * S_LEN) * DH;

  // all-ones flags for both 64-row halves of this 128-row q-block
  const uint fmask = PRE ? (F[(q0 >> 6)] & F[(q0 >> 6) + 1]) : 0u;

  // ---- Q fragments, 2 per wave (rows w*32 + f*16 + qr) ----
  bf16x8 qf[2][2];
#pragma unroll
  for (int f = 0; f < 2; ++f) {
    const float* qp = Qb + (size_t)(q0 + w * 32 + f * 16 + qr) * DH + kg * 8;
#pragma unroll
    for (int ks = 0; ks < 2; ++ks) {
      float4 a = *(const float4*)(qp + ks * 32);
      float4 b = *(const float4*)(qp + ks * 32 + 4);
      bf16x8 t2;
      t2[0]=(bf16)(a.x*QSCALE); t2[1]=(bf16)(a.y*QSCALE);
      t2[2]=(bf16)(a.z*QSCALE); t2[3]=(bf16)(a.w*QSCALE);
      t2[4]=(bf16)(b.x*QSCALE); t2[5]=(bf16)(b.y*QSCALE);
      t2[6]=(bf16)(b.z*QSCALE); t2[7]=(bf16)(b.w*QSCALE);
      qf[f][ks] = t2;
    }
  }

  f32x4 acc[2][4];
#pragma unroll
  for (int f = 0; f < 2; ++f)
#pragma unroll
    for (int nt = 0; nt < 4; ++nt) { f32x4 z = {0.f,0.f,0.f,0.f}; acc[f][nt] = z; }
  float mrow[2] = {-1e30f, -1e30f};
  float rsum[2] = {0.f, 0.f};

  // loop-invariant LDS byte offsets (K-read and V-read formulas coincide)
  int lofs[4][2];
#pragma unroll
  for (int x = 0; x < 4; ++x) {
    const int row = 16 * x + qr;
    const int sw  = SWZ(row);
#pragma unroll
    for (int ks = 0; ks < 2; ++ks)
      lofs[x][ks] = row * 128 + ((kg * 16 + 64 * ks) ^ sw);
  }
  char* pb0 = (char*)pbw + (w * 32 + qr) * 128;        // frag 0 row
  char* pb1 = pb0 + 16 * 128;                          // frag 1 row
  const int psw = (qr & 7) << 4;

  // staging decomposition (fallback path)
  const int kr0 = tid >> 3, kc8 = tid & 7;
  const int vr = (tid >> 4) * 4, vc = (tid & 15) * 4;

  for (int t = 0; t < NT; ++t) {
    // ---- stage tile t ----
    if (PRE) {
      const char* ksrc = kws + ((size_t)bh * NT + t) * TILE_BYTES;
      const char* vsrc = vws + ((size_t)bh * NT + t) * TILE_BYTES;
#pragma unroll
      for (int c = 0; c < 2; ++c) {
        const int off = (w + c * 4) * 1024 + lane * 16;
        gload16(ksrc + off, (char*)kb + off);
        gload16(vsrc + off, (char*)vb + off);
      }
    } else {
      const int kv0 = t * KVBLK;
#pragma unroll
      for (int h = 0; h < 2; ++h) {
        const int row = kr0 + 32 * h;
        const float* kp = Kb + (size_t)(kv0 + row) * DH + kc8 * 8;
        float4 a = *(const float4*)kp;
        float4 b = *(const float4*)(kp + 4);
        ushort8v pk;
        pk[0]=bfb(a.x); pk[1]=bfb(a.y); pk[2]=bfb(a.z); pk[3]=bfb(a.w);
        pk[4]=bfb(b.x); pk[5]=bfb(b.y); pk[6]=bfb(b.z); pk[7]=bfb(b.w);
        *(ushort8v*)((char*)kb + row * 128 + ((kc8 * 16) ^ SWZ(row))) = pk;
      }
      float rr[4][4];
#pragma unroll
      for (int i = 0; i < 4; ++i)
        *(float4*)rr[i] = *(const float4*)(Vb + (size_t)(kv0 + vr + i) * DH + vc);
#pragma unroll
      for (int c = 0; c < 4; ++c) {
        const int d = vc + c;
        ushort4v p4;
        p4[0]=bfb(rr[0][c]); p4[1]=bfb(rr[1][c]);
        p4[2]=bfb(rr[2][c]); p4[3]=bfb(rr[3][c]);
        *(ushort4v*)((char*)vb + d * 128 + ((vr * 2) ^ SWZ(d))) = p4;
      }
    }
    __syncthreads();   // staged tile visible

    // ---- S^T = K Q^T, both q-frags share every K-fragment read ----
    f32x4 sc[2][4];
    __builtin_amdgcn_s_setprio(1);
#pragma unroll
    for (int ct = 0; ct < 4; ++ct) {
      f32x4 z = {0.f,0.f,0.f,0.f};
      sc[0][ct] = z; sc[1][ct] = z;
#pragma unroll
      for (int ks = 0; ks < 2; ++ks) {
        bf16x8 kf = *(const bf16x8*)((const char*)kb + lofs[ct][ks]);
        sc[0][ct] = __builtin_amdgcn_mfma_f32_16x16x32_bf16(kf, qf[0][ks], sc[0][ct], 0,0,0);
        sc[1][ct] = __builtin_amdgcn_mfma_f32_16x16x32_bf16(kf, qf[1][ks], sc[1][ct], 0,0,0);
      }
    }
    __builtin_amdgcn_s_setprio(0);

    const bool allset = PRE ? (((fmask >> t) & 1u) != 0u) : false;

    // ---- per-frag in-register online softmax + P write ----
#pragma unroll
    for (int f = 0; f < 2; ++f) {
      if (!allset) {
        const size_t mo = (size_t)(q0 + w * 32 + f * 16 + qr) * S_LEN
                          + t * KVBLK + 4 * kg;
#pragma unroll
        for (int ct = 0; ct < 4; ++ct)
#pragma unroll
          for (int r = 0; r < 4; ++r)
            if (M[mo + 16 * ct + r] == 0) sc[f][ct][r] = NEG;
      }

      float a0 = fmaxf(fmaxf(sc[f][0][0], sc[f][0][1]), sc[f][0][2]);
      float a1 = fmaxf(fmaxf(sc[f][0][3], sc[f][1][0]), sc[f][1][1]);
      float a2 = fmaxf(fmaxf(sc[f][1][2], sc[f][1][3]), sc[f][2][0]);
      float a3 = fmaxf(fmaxf(sc[f][2][1], sc[f][2][2]), sc[f][2][3]);
      float a4 = fmaxf(fmaxf(sc[f][3][0], sc[f][3][1]), sc[f][3][2]);
      float lm = fmaxf(fmaxf(a0, a1), a2);
      lm = fmaxf(fmaxf(lm, a3), a4);
      lm = fmaxf(lm, sc[f][3][3]);
      lm = fmaxf(lm, __shfl_xor(lm, 16));
      lm = fmaxf(lm, __shfl_xor(lm, 32));

      if (!__all(lm - mrow[f] <= THR)) {   // defer-max (T13)
        const float mnew = fmaxf(mrow[f], lm);
        const float corr = __builtin_amdgcn_exp2f(mrow[f] - mnew);
        rsum[f] *= corr;
#pragma unroll
        for (int nt = 0; nt < 4; ++nt) acc[f][nt] *= corr;
        mrow[f] = mnew;
      }

      float p[4][4];
      float ps = 0.f;
#pragma unroll
      for (int ct = 0; ct < 4; ++ct)
#pragma unroll
        for (int r = 0; r < 4; ++r) {
          p[ct][r] = __builtin_amdgcn_exp2f(sc[f][ct][r] - mrow[f]);
          ps += p[ct][r];
        }
      rsum[f] += ps;

      char* pb = f ? pb1 : pb0;
#pragma unroll
      for (int ct = 0; ct < 4; ++ct) {
        uint2v d2;
        d2[0] = cvtpk(p[ct][0], p[ct][1]);
        d2[1] = cvtpk(p[ct][2], p[ct][3]);
        *(uint2v*)(pb + ((32 * ct + 8 * kg) ^ psw)) = d2;
      }
    }

    // ---- O^T += V^T P^T, both q-frags share every V-fragment read ----
    __builtin_amdgcn_s_setprio(1);
#pragma unroll
    for (int ks = 0; ks < 2; ++ks) {
      bf16x8 pf0 = *(const bf16x8*)(pb0 + ((kg * 16 + 64 * ks) ^ psw));
      bf16x8 pf1 = *(const bf16x8*)(pb1 + ((kg * 16 + 64 * ks) ^ psw));
#pragma unroll
      for (int nt = 0; nt < 4; ++nt) {
        bf16x8 vf = *(const bf16x8*)((const char*)vb + lofs[nt][ks]);
        acc[0][nt] = __builtin_amdgcn_mfma_f32_16x16x32_bf16(vf, pf0, acc[0][nt], 0,0,0);
        acc[1][nt] = __builtin_amdgcn_mfma_f32_16x16x32_bf16(vf, pf1, acc[1][nt], 0,0,0);
      }
    }
    __builtin_amdgcn_s_setprio(0);

    __syncthreads();   // all reads of tile t done before next stage
  }

  // ---- epilogue ----
#pragma unroll
  for (int f = 0; f < 2; ++f) {
    float rs = rsum[f];
    rs += __shfl_xor(rs, 16);
    rs += __shfl_xor(rs, 32);
    const float inv = 1.0f / rs;
    float* Ob = O + ((size_t)bh * S_LEN + q0 + w * 32 + f * 16 + qr) * DH;
#pragma unroll
    for (int nt = 0; nt < 4; ++nt) {
      float4 o = { acc[f][nt][0] * inv, acc[f][nt][1] * inv,
                   acc[f][nt][2] * inv, acc[f][nt][3] * inv };
      *(float4*)(Ob + 16 * nt + 4 * kg) = o;
    }
  }
}

extern "C" void kernel_launch(void* const* d_in, const int* in_sizes, int n_in,
                              void* d_out, int out_size, void* d_ws, size_t ws_size,
                              hipStream_t stream)
{
  const float* Q = (const float*)d_in[0];
  const float* K = (const float*)d_in[1];
  const float* V = (const float*)d_in[2];
  const int*   M = (const int*)d_in[3];
  float* O = (float*)d_out;

  const size_t need = 4096 + 2 * KV_BYTES;
  const bool pre = (d_ws != nullptr) && (ws_size >= need);

  dim3 grid(S_LEN / QBLK, 4 * 16);   // 16 q-blocks x 64 (b,h) = 1024 wgs
  if (pre) {
    uint* F   = (uint*)d_ws;
    char* kws = (char*)d_ws + 4096;
    char* vws = kws + KV_BYTES;
    hipMemsetAsync(F, 0, 32 * sizeof(uint), stream);
    mask_flags<<<dim3(32, 8), 256, 0, stream>>>(M, F);
    cvt_kv<<<dim3(NT, 64), 256, 0, stream>>>(K, V, kws, vws);
    attn_fwd<true><<<grid, NWAVE * 64, 0, stream>>>(Q, K, V, M, F, kws, vws, O);
  } else {
    attn_fwd<false><<<grid, NWAVE * 64, 0, stream>>>(Q, K, V, M, nullptr, nullptr, nullptr, O);
  }
}

// Round 16
// 123.782 us; speedup vs baseline: 1.5534x; 1.0195x over previous
//
#include <hip/hip_runtime.h>

typedef __bf16 bf16;
typedef __attribute__((ext_vector_type(8))) __bf16 bf16x8;
typedef __attribute__((ext_vector_type(8))) ushort ushort8v;
typedef __attribute__((ext_vector_type(4))) ushort ushort4v;
typedef __attribute__((ext_vector_type(16))) float f32x16;

constexpr int S_LEN = 2048;
constexpr int DH    = 64;
constexpr int QBLK  = 128;                       // 4 waves x 32 q-rows
constexpr int KVBLK = 64;
constexpr int NWAVE = 4;
constexpr int NT    = S_LEN / KVBLK;             // 32 kv tiles
constexpr float QSCALE = 0.125f * 1.44269504088896f;  // 1/sqrt(64) * log2(e)
constexpr float NEG    = -1.44269504e9f;         // -1e9 in log2 domain
constexpr float THR    = 8.0f;                   // defer-max threshold (T13)
constexpr size_t TILE_BYTES = (size_t)KVBLK * DH * 2;       // 8 KiB
constexpr size_t KV_BYTES   = (size_t)64 * NT * TILE_BYTES; // 16 MiB per tensor

__device__ __forceinline__ ushort bfb(float f) {
  bf16 b = (bf16)f;
  return __builtin_bit_cast(ushort, b);
}
__device__ __forceinline__ int SWZ(int row) {
  return ((row & 7) ^ ((row >> 3) & 7)) << 4;
}
__device__ __forceinline__ uint cvtpk(float lo, float hi) {
  uint r;
  asm("v_cvt_pk_bf16_f32 %0, %1, %2" : "=v"(r) : "v"(lo), "v"(hi));
  return r;
}
__device__ __forceinline__ void gload16(const char* g, void* l) {
  __builtin_amdgcn_global_load_lds(
      (__attribute__((address_space(1))) void*)(g),
      (__attribute__((address_space(3))) void*)(l), 16, 0, 0);
}

// ---- prepass: parallel all-ones tile flags ----
__global__ __launch_bounds__(256)
void mask_flags(const int* __restrict__ M, uint* __restrict__ F) {
  const int qt  = blockIdx.x;
  const int kt0 = blockIdx.y * 4;
  const int tid = threadIdx.x;
  const int r  = tid >> 2;
  const int c0 = (tid & 3) * 16;
  __shared__ int s[4];
  uint bits = 0;
  for (int i = 0; i < 4; ++i) {
    const int kt = kt0 + i;
    const int* row = M + (size_t)(qt * 64 + r) * S_LEN + kt * 64 + c0;
    int ok = 1;
#pragma unroll
    for (int j = 0; j < 4; ++j) {
      int4 v = *(const int4*)(row + j * 4);
      ok &= (v.x != 0) & (v.y != 0) & (v.z != 0) & (v.w != 0);
    }
    ok = __all(ok) ? 1 : 0;
    if ((tid & 63) == 0) s[tid >> 6] = ok;
    __syncthreads();
    if (s[0] & s[1] & s[2] & s[3]) bits |= 1u << kt;
    __syncthreads();
  }
  if (tid == 0) atomicOr(&F[qt], bits);
}

// ---- prepass: K -> bf16 swizzled tile blobs; V -> V^T bf16 swizzled blobs ----
__global__ __launch_bounds__(256)
void cvt_kv(const float* __restrict__ K, const float* __restrict__ V,
            char* __restrict__ kws, char* __restrict__ vws) {
  const int t = blockIdx.x, bh = blockIdx.y, tid = threadIdx.x;
  const float* Kb = K + ((size_t)bh * S_LEN + t * KVBLK) * DH;
  const float* Vb = V + ((size_t)bh * S_LEN + t * KVBLK) * DH;
  char* kd = kws + ((size_t)bh * NT + t) * TILE_BYTES;
  char* vd = vws + ((size_t)bh * NT + t) * TILE_BYTES;

  const int kr0 = tid >> 3, kc8 = tid & 7;
#pragma unroll
  for (int h = 0; h < 2; ++h) {
    const int row = kr0 + 32 * h;
    const float* kp = Kb + (size_t)row * DH + kc8 * 8;
    float4 a = *(const float4*)kp;
    float4 b = *(const float4*)(kp + 4);
    ushort8v pk;
    pk[0]=bfb(a.x); pk[1]=bfb(a.y); pk[2]=bfb(a.z); pk[3]=bfb(a.w);
    pk[4]=bfb(b.x); pk[5]=bfb(b.y); pk[6]=bfb(b.z); pk[7]=bfb(b.w);
    *(ushort8v*)(kd + row * 128 + ((kc8 * 16) ^ SWZ(row))) = pk;
  }
  const int vr = (tid >> 4) * 4, vc = (tid & 15) * 4;
  float rr[4][4];
#pragma unroll
  for (int i = 0; i < 4; ++i)
    *(float4*)rr[i] = *(const float4*)(Vb + (size_t)(vr + i) * DH + vc);
#pragma unroll
  for (int c = 0; c < 4; ++c) {
    const int d = vc + c;
    ushort4v p4;
    p4[0]=bfb(rr[0][c]); p4[1]=bfb(rr[1][c]);
    p4[2]=bfb(rr[2][c]); p4[3]=bfb(rr[3][c]);
    *(ushort4v*)(vd + d * 128 + ((vr * 2) ^ SWZ(d))) = p4;
  }
}

// ---- main: 32x32 MFMA, in-register softmax+P (T12), no P-LDS ----
// Each wave owns 32 q-rows (q = q0 + w*32 + lane&31); lane l and l+32 share
// a q-row, holding complementary kv/d rows. LDS = K/V tiles only (16 KB).
template<bool PRE>
__global__ __launch_bounds__(256, 4)
void attn_fwd(const float* __restrict__ Q, const float* __restrict__ K,
              const float* __restrict__ V, const int* __restrict__ M,
              const uint* __restrict__ F, const char* __restrict__ kws,
              const char* __restrict__ vws, float* __restrict__ O)
{
  __shared__ __align__(16) ushort kb[KVBLK * DH];        // [kv][d] swizzled
  __shared__ __align__(16) ushort vb[DH * KVBLK];        // [d][kv] swizzled

  const int tid  = threadIdx.x;
  const int lane = tid & 63;
  const int w    = tid >> 6;
  const int ql   = lane & 31;   // q within wave block; MFMA row/col index
  const int h    = lane >> 5;   // lane half

  // XCD-aware bijective block swizzle (1024 % 8 == 0)
  const int flat = blockIdx.y * gridDim.x + blockIdx.x;
  const int nid  = (flat & 7) * 128 + (flat >> 3);
  const int q0   = (nid & 15) * QBLK;
  const int bh   = nid >> 4;

  const float* Qb = Q + ((size_t)bh * S_LEN) * DH;
  const float* Kb = K + ((size_t)bh * S_LEN) * DH;
  const float* Vb = V + ((size_t)bh * S_LEN) * DH;

  const uint fmask = PRE ? (F[(q0 >> 6)] & F[(q0 >> 6) + 1]) : 0u;

  // ---- Q fragments (B-operand): qf[s] = Q[q][16s+8h+j]*QSCALE, j=0..7 ----
  bf16x8 qf[4];
  {
    const float* qp = Qb + (size_t)(q0 + w * 32 + ql) * DH + 8 * h;
#pragma unroll
    for (int s = 0; s < 4; ++s) {
      float4 a = *(const float4*)(qp + 16 * s);
      float4 b = *(const float4*)(qp + 16 * s + 4);
      bf16x8 t2;
      t2[0]=(bf16)(a.x*QSCALE); t2[1]=(bf16)(a.y*QSCALE);
      t2[2]=(bf16)(a.z*QSCALE); t2[3]=(bf16)(a.w*QSCALE);
      t2[4]=(bf16)(b.x*QSCALE); t2[5]=(bf16)(b.y*QSCALE);
      t2[6]=(bf16)(b.z*QSCALE); t2[7]=(bf16)(b.w*QSCALE);
      qf[s] = t2;
    }
  }

  f32x16 acc0, acc1;            // O^T d-tiles 0,1
#pragma unroll
  for (int i = 0; i < 16; ++i) { acc0[i] = 0.f; acc1[i] = 0.f; }
  float mrow = -1e30f;
  float rsum = 0.f;

  // LDS byte offsets: row = 32x+ql (kv for K, d for V), col byte 32s+16h
  int kofs[2][4];
#pragma unroll
  for (int x = 0; x < 2; ++x) {
    const int row = 32 * x + ql;
    const int sw  = SWZ(row);
#pragma unroll
    for (int s = 0; s < 4; ++s)
      kofs[x][s] = row * 128 + ((32 * s + 16 * h) ^ sw);
  }

  // P-pack: 8 exp'd scores (j order) -> PV B-frag via lane+-32 exchange
  auto mkfrag = [&](float p0, float p1, float p2, float p3,
                    float p4, float p5, float p6, float p7) -> bf16x8 {
    uint a0 = cvtpk(p0, p1), a1 = cvtpk(p2, p3);
    uint b0 = cvtpk(p4, p5), b1 = cvtpk(p6, p7);
    uint ta0 = __shfl_xor(a0, 32), ta1 = __shfl_xor(a1, 32);
    uint tb0 = __shfl_xor(b0, 32), tb1 = __shfl_xor(b1, 32);
    uint4 wv;
    wv.x = h ? tb0 : a0;
    wv.y = h ? tb1 : a1;
    wv.z = h ? b0  : ta0;
    wv.w = h ? b1  : ta1;
    return __builtin_bit_cast(bf16x8, wv);
  };

  // staging decomposition (fallback path)
  const int kr0 = tid >> 3, kc8 = tid & 7;
  const int vr = (tid >> 4) * 4, vc = (tid & 15) * 4;

  for (int t = 0; t < NT; ++t) {
    // ---- stage tile t ----
    if (PRE) {
      const char* ksrc = kws + ((size_t)bh * NT + t) * TILE_BYTES;
      const char* vsrc = vws + ((size_t)bh * NT + t) * TILE_BYTES;
#pragma unroll
      for (int c = 0; c < 2; ++c) {
        const int off = (w + c * 4) * 1024 + lane * 16;
        gload16(ksrc + off, (char*)kb + off);
        gload16(vsrc + off, (char*)vb + off);
      }
    } else {
#pragma unroll
      for (int hh = 0; hh < 2; ++hh) {
        const int row = kr0 + 32 * hh;
        const float* kp = Kb + (size_t)(t * KVBLK + row) * DH + kc8 * 8;
        float4 a = *(const float4*)kp;
        float4 b = *(const float4*)(kp + 4);
        ushort8v pk;
        pk[0]=bfb(a.x); pk[1]=bfb(a.y); pk[2]=bfb(a.z); pk[3]=bfb(a.w);
        pk[4]=bfb(b.x); pk[5]=bfb(b.y); pk[6]=bfb(b.z); pk[7]=bfb(b.w);
        *(ushort8v*)((char*)kb + row * 128 + ((kc8 * 16) ^ SWZ(row))) = pk;
      }
      float rr[4][4];
#pragma unroll
      for (int i = 0; i < 4; ++i)
        *(float4*)rr[i] = *(const float4*)(Vb + (size_t)(t * KVBLK + vr + i) * DH + vc);
#pragma unroll
      for (int c = 0; c < 4; ++c) {
        const int d = vc + c;
        ushort4v p4;
        p4[0]=bfb(rr[0][c]); p4[1]=bfb(rr[1][c]);
        p4[2]=bfb(rr[2][c]); p4[3]=bfb(rr[3][c]);
        *(ushort4v*)((char*)vb + d * 128 + ((vr * 2) ^ SWZ(d))) = p4;
      }
    }
    __syncthreads();

    // ---- S^T = K Q^T : 2 kv-tiles x 4 k-steps (8 mfma_32x32x16) ----
    // lane holds S[kv = 32*tau + (reg&3)+8*(reg>>2)+4h][q = ql]
    f32x16 sc0, sc1;
#pragma unroll
    for (int i = 0; i < 16; ++i) { sc0[i] = 0.f; sc1[i] = 0.f; }

    __builtin_amdgcn_s_setprio(1);
#pragma unroll
    for (int s = 0; s < 4; ++s) {
      bf16x8 k0 = *(const bf16x8*)((const char*)kb + kofs[0][s]);
      bf16x8 k1 = *(const bf16x8*)((const char*)kb + kofs[1][s]);
      sc0 = __builtin_amdgcn_mfma_f32_32x32x16_bf16(k0, qf[s], sc0, 0,0,0);
      sc1 = __builtin_amdgcn_mfma_f32_32x32x16_bf16(k1, qf[s], sc1, 0,0,0);
    }
    __builtin_amdgcn_s_setprio(0);

    const bool allset = PRE ? (((fmask >> t) & 1u) != 0u) : false;
    if (!allset) {
      const size_t mo = (size_t)(q0 + w * 32 + ql) * S_LEN + t * KVBLK + 4 * h;
#pragma unroll
      for (int r = 0; r < 16; ++r) {
        const int cr = (r & 3) + 8 * (r >> 2);
        if (M[mo + cr] == 0)      sc0[r] = NEG;
        if (M[mo + 32 + cr] == 0) sc1[r] = NEG;
      }
    }

    // ---- in-register online softmax (one q-row per lane-pair) ----
    float lm = fmaxf(sc0[0], sc0[1]);
#pragma unroll
    for (int i = 2; i < 16; ++i) lm = fmaxf(lm, sc0[i]);
#pragma unroll
    for (int i = 0; i < 16; ++i) lm = fmaxf(lm, sc1[i]);
    lm = fmaxf(lm, __shfl_xor(lm, 32));

    if (!__all(lm - mrow <= THR)) {      // defer-max (T13)
      const float mnew = fmaxf(mrow, lm);
      const float corr = __builtin_amdgcn_exp2f(mrow - mnew);
      rsum *= corr;
      acc0 *= corr;
      acc1 *= corr;
      mrow = mnew;
    }

    float ps = 0.f;
#pragma unroll
    for (int i = 0; i < 16; ++i) {
      sc0[i] = __builtin_amdgcn_exp2f(sc0[i] - mrow); ps += sc0[i];
      sc1[i] = __builtin_amdgcn_exp2f(sc1[i] - mrow); ps += sc1[i];
    }
    rsum += ps;

    // ---- P -> PV B-frags, fully in-register (T12) ----
    bf16x8 pf[4];
    pf[0] = mkfrag(sc0[0], sc0[1], sc0[2],  sc0[3],  sc0[4],  sc0[5],  sc0[6],  sc0[7]);
    pf[1] = mkfrag(sc0[8], sc0[9], sc0[10], sc0[11], sc0[12], sc0[13], sc0[14], sc0[15]);
    pf[2] = mkfrag(sc1[0], sc1[1], sc1[2],  sc1[3],  sc1[4],  sc1[5],  sc1[6],  sc1[7]);
    pf[3] = mkfrag(sc1[8], sc1[9], sc1[10], sc1[11], sc1[12], sc1[13], sc1[14], sc1[15]);

    // ---- O^T += V^T P^T : 2 d-tiles x 4 kv-steps ----
    __builtin_amdgcn_s_setprio(1);
#pragma unroll
    for (int s = 0; s < 4; ++s) {
      bf16x8 v0 = *(const bf16x8*)((const char*)vb + kofs[0][s]);
      bf16x8 v1 = *(const bf16x8*)((const char*)vb + kofs[1][s]);
      acc0 = __builtin_amdgcn_mfma_f32_32x32x16_bf16(v0, pf[s], acc0, 0,0,0);
      acc1 = __builtin_amdgcn_mfma_f32_32x32x16_bf16(v1, pf[s], acc1, 0,0,0);
    }
    __builtin_amdgcn_s_setprio(0);

    __syncthreads();
  }

  // ---- epilogue: O[q][d] = acc / rsum ----
  rsum += __shfl_xor(rsum, 32);
  const float inv = 1.0f / rsum;
  float* Ob = O + ((size_t)bh * S_LEN + q0 + w * 32 + ql) * DH + 4 * h;
#pragma unroll
  for (int g = 0; g < 4; ++g) {
    float4 o0 = { acc0[4*g+0]*inv, acc0[4*g+1]*inv, acc0[4*g+2]*inv, acc0[4*g+3]*inv };
    float4 o1 = { acc1[4*g+0]*inv, acc1[4*g+1]*inv, acc1[4*g+2]*inv, acc1[4*g+3]*inv };
    *(float4*)(Ob + 8 * g)      = o0;
    *(float4*)(Ob + 32 + 8 * g) = o1;
  }
}

extern "C" void kernel_launch(void* const* d_in, const int* in_sizes, int n_in,
                              void* d_out, int out_size, void* d_ws, size_t ws_size,
                              hipStream_t stream)
{
  const float* Q = (const float*)d_in[0];
  const float* K = (const float*)d_in[1];
  const float* V = (const float*)d_in[2];
  const int*   M = (const int*)d_in[3];
  float* O = (float*)d_out;

  const size_t need = 4096 + 2 * KV_BYTES;
  const bool pre = (d_ws != nullptr) && (ws_size >= need);

  dim3 grid(S_LEN / QBLK, 4 * 16);   // 16 q-blocks x 64 (b,h) = 1024 wgs
  if (pre) {
    uint* F   = (uint*)d_ws;
    char* kws = (char*)d_ws + 4096;
    char* vws = kws + KV_BYTES;
    hipMemsetAsync(F, 0, 32 * sizeof(uint), stream);
    mask_flags<<<dim3(32, 8), 256, 0, stream>>>(M, F);
    cvt_kv<<<dim3(NT, 64), 256, 0, stream>>>(K, V, kws, vws);
    attn_fwd<true><<<grid, NWAVE * 64, 0, stream>>>(Q, K, V, M, F, kws, vws, O);
  } else {
    attn_fwd<false><<<grid, NWAVE * 64, 0, stream>>>(Q, K, V, M, nullptr, nullptr, nullptr, O);
  }
}